// Round 11
// baseline (215.749 us; speedup 1.0000x reference)
//
#include <hip/hip_runtime.h>
#include <math.h>

#define EPS32 1.1920928955078125e-07f
#define NSP 32768          // 2*128*128 spatial positions
#define HB 128             // heatmap blocks

typedef float v4f __attribute__((ext_vector_type(4)));
typedef float v2f __attribute__((ext_vector_type(2)));

// ---------------- ws layout (float units) ----------------
// 0     : partial[128]
// 1024  : hmv[32768]

__device__ __forceinline__ float gauss_radius(float h, float w) {
#pragma clang fp contract(off)
    const float mo = 0.1f;
    float b1 = h + w;
    float c1 = w * h * (1.0f - mo) / (1.0f + mo);
    float r1 = (b1 + sqrtf(fmaxf(b1 * b1 - 4.0f * c1, 0.0f))) / 2.0f;
    float b2 = 2.0f * (h + w);
    float c2 = (1.0f - mo) * w * h;
    float r2 = (b2 + sqrtf(fmaxf(b2 * b2 - 16.0f * c2, 0.0f))) / 2.0f;
    float b3 = -2.0f * mo * (h + w);
    float c3 = (mo - 1.0f) * w * h;
    float r3 = (b3 + sqrtf(fmaxf(b3 * b3 - 16.0f * mo * c3, 0.0f))) / 2.0f;
    return fminf(fminf(r1, r2), r3);
}

// Heatmap: 128 blocks, per-block in-LDS box params + per-block partial sum.
__global__ void k_heat(const float* __restrict__ boxes, int N,
                       float* __restrict__ hmv, float* __restrict__ partial) {
    int bx = blockIdx.x;
    int tid = threadIdx.x;
    __shared__ int   s_cxi[128], s_cyi[128], s_czi[128], s_rx[128], s_rz[128];
    __shared__ float s_ix[128], s_iz[128];
    if (tid < N) {
#pragma clang fp contract(off)
        int b = tid;
        float x = boxes[b * 9 + 0];
        float y = boxes[b * 9 + 1];
        float z = boxes[b * 9 + 2];
        float wf = boxes[b * 9 + 3] / 0.1f / 8.0f;
        float lf = boxes[b * 9 + 4] / 0.1f / 8.0f;
        float hf = boxes[b * 9 + 5] / 0.2f / 8.0f;
        float r_xy = gauss_radius(lf, wf);
        float r_z  = fmaxf(gauss_radius(lf, hf), gauss_radius(wf, hf));
        int rx = max(2, (int)truncf(r_xy / 0.4f));
        int rz = max(2, (int)truncf(r_z / 1.0f));
        float cx = (x + 51.2f) / 0.4f;
        float cy = (y + 51.2f) / 0.4f;
        float cz = (z + 5.0f) / 1.0f;
        int cxi = (int)cx, cyi = (int)cy, czi = (int)cz;
        int valid = (wf > 0.0f) && (lf > 0.0f) &&
                    cxi >= 0 && cxi < 128 && cyi >= 0 && cyi < 128 &&
                    czi >= 0 && czi <= 1;
        float sx = (2.0f * (float)rx + 1.0f) / 6.0f;
        float sz = (2.0f * (float)rz + 1.0f) / 6.0f;
        s_cxi[b] = cxi;
        s_cyi[b] = cyi;
        s_czi[b] = czi;
        s_rx[b]  = valid ? rx : -1;   // rx=-1 makes window test always fail
        s_rz[b]  = rz;
        s_ix[b]  = 1.0f / (2.0f * sx * sx);
        s_iz[b]  = 1.0f / (2.0f * sz * sz);
    }
    __syncthreads();

    int i = bx * 256 + tid;
    int y = i & 127, x = (i >> 7) & 127, zc = i >> 14;
    float m = 0.0f;
    for (int b = 0; b < N; ++b) {
        int rx = s_rx[b];
        int dx = x - s_cxi[b];
        if (dx > rx || dx < -rx) continue;
        int dy = y - s_cyi[b];
        if (dy > rx || dy < -rx) continue;
        int rz = s_rz[b];
        int dz = zc - s_czi[b];
        if (dz > rz || dz < -rz) continue;
        float e = (float)(dx * dx + dy * dy) * s_ix[b]
                + (float)(dz * dz) * s_iz[b];
        float g = expf(-e);
        if (g >= EPS32) m = fmaxf(m, g);
    }
    hmv[i] = m;
    __shared__ float sm[256];
    sm[tid] = m;
    __syncthreads();
    for (int s = 128; s > 0; s >>= 1) {
        if (tid < s) sm[tid] += sm[tid + s];
        __syncthreads();
    }
    if (tid == 0) partial[bx] = sm[0];
}

// ONE-PASS pool + GEMM + epilogue, R10 defects fixed:
//  (1) pool loads now PERFECTLY coalesced: per wave-iter, one channel's
//      4 rows x 128 floats = 2KB loaded as two dense 1KB instructions
//      (lane addr stride exactly 16B); row-pair combine via shfl_xor(32).
//      (R10 had 32B lane stride with 16B loads -> half-dense + nt refetch.)
//  (2) sW even/odd-quad layout: GEMM W-reads drop from 4-way LDS conflict
//      to 2-way (free per m136).
// Traffic: student 67MB once (nt), W 32KB/block (L2-hot), teacher 16.8 (nt),
// out 16.8 (nt). LDS: sP 16KB + sW 32KB = 48KB -> 2 blocks/CU at 512 blocks.
__global__ __launch_bounds__(256, 2)
void k_gemm(const float* __restrict__ S, const float* __restrict__ T,
            const float* __restrict__ W, const float* __restrict__ Bb,
            const float* __restrict__ hmv, const float* __restrict__ partial,
            float* __restrict__ out) {
    __shared__ float sP[64 * 64];    // [c][sp]
    __shared__ float sW[64 * 128];   // [c][even-quads(64) | odd-quads(64)]
    __shared__ float s_scale;

    int tid = threadIdx.x;
    int b   = blockIdx.x;            // 512 sp-tiles of 64
    int d   = b >> 8;
    int h   = (b >> 1) & 127;
    int w0  = (b & 1) * 64;
    int zl  = d ? 5 : 1;

    if (tid < 64) {
        float v = partial[tid] + partial[tid + 64];
        for (int off = 32; off > 0; off >>= 1) v += __shfl_down(v, off, 64);
        if (tid == 0) s_scale = 10.0f / (v + 1e-4f);
    }

    // ---- stage W: thread (o = tid>>1, c-half) -> sW[c][evenodd(o)]
    {
        int o  = tid >> 1;
        int c0 = (tid & 1) * 32;
        int ob = ((o >> 2) & 1) * 64 + (o >> 3) * 4 + (o & 3);  // even/odd-quad pos
        const v4f* Wg = (const v4f*)(W + o * 64 + c0);
#pragma unroll
        for (int k = 0; k < 8; ++k) {
            v4f wv = Wg[k];
            int c = c0 + 4 * k;
            sW[(c    ) * 128 + ob] = wv.x;
            sW[(c + 1) * 128 + ob] = wv.y;
            sW[(c + 2) * 128 + ob] = wv.z;
            sW[(c + 3) * 128 + ob] = wv.w;
        }
    }

    // ---- pool: wave wv handles c = wv*16 .. +16; per c load 2KB dense
    {
        int wv   = tid >> 6;
        int lane = tid & 63;
        int rsel = lane >> 5;            // 0: rows {2h,z0 ; 2h,z1}, 1: rows {2h+1,...}
        int cq   = lane & 31;            // 16B column chunk
        long rowA = (long)rsel * 256;            // z0: row 2h or 2h+1
        long rowB = 65536 + rowA;                // z1: same row
#pragma unroll 4
        for (int it = 0; it < 16; ++it) {
            int c = wv * 16 + it;
            const float* base = S + (long)(c * 8 + zl) * 65536 + (2 * h) * 256 + 2 * w0;
            v4f a  = __builtin_nontemporal_load((const v4f*)(base + rowA) + cq);
            v4f bq = __builtin_nontemporal_load((const v4f*)(base + rowB) + cq);
            float sx = (a.x + a.y) + (bq.x + bq.y);   // w-pair 2cq, rows rsel(z0)+rsel(z1)
            float sy = (a.z + a.w) + (bq.z + bq.w);   // w-pair 2cq+1
            sx += __shfl_xor(sx, 32, 64);             // + other row pair
            sy += __shfl_xor(sy, 32, 64);
            if (lane < 32) {
                v2f pv = {sx * 0.125f, sy * 0.125f};
                *(v2f*)&sP[c * 64 + 2 * cq] = pv;     // banks 2-way = free
            }
        }
    }

    __syncthreads();

    // ---- GEMM: og = tid>>4 (8 o), sq = tid&15 (4 sp)
    int og = tid >> 4, sq = tid & 15;
    int o0 = og * 8;

    v4f acc[8];
#pragma unroll
    for (int oo = 0; oo < 8; ++oo) {
        float bv = Bb[o0 + oo];
        acc[oo] = (v4f){bv, bv, bv, bv};
    }

#pragma unroll 8
    for (int c = 0; c < 64; ++c) {
        v4f p  = *(const v4f*)&sP[c * 64 + 4 * sq];        // 2-way = free
        v4f wa = *(const v4f*)&sW[c * 128 + 4 * og];       // even quad 2og (o0..o0+3)
        v4f wb = *(const v4f*)&sW[c * 128 + 64 + 4 * og];  // odd quad 2og+1 (o0+4..)
        acc[0] += wa.x * p;
        acc[1] += wa.y * p;
        acc[2] += wa.z * p;
        acc[3] += wa.w * p;
        acc[4] += wb.x * p;
        acc[5] += wb.y * p;
        acc[6] += wb.z * p;
        acc[7] += wb.w * p;
    }

    // ---- epilogue: |acc - T| * hmv * scale (all read/write-once -> nt)
    float sc = s_scale;
    v4f hm = *(const v4f*)&hmv[b * 64 + sq * 4];
    v4f hw = hm * sc;
    const v4f* T4 = (const v4f*)T;
    v4f* O4 = (v4f*)out;
    long base_o = (long)o0 * (NSP / 4) + b * 16 + sq;
#pragma unroll
    for (int oo = 0; oo < 8; ++oo) {
        v4f tv = __builtin_nontemporal_load(&T4[base_o + (long)oo * (NSP / 4)]);
        v4f df = acc[oo] - tv;
        v4f r;
        r.x = fabsf(df.x) * hw.x;
        r.y = fabsf(df.y) * hw.y;
        r.z = fabsf(df.z) * hw.z;
        r.w = fabsf(df.w) * hw.w;
        __builtin_nontemporal_store(r, &O4[base_o + (long)oo * (NSP / 4)]);
    }
}

extern "C" void kernel_launch(void* const* d_in, const int* in_sizes, int n_in,
                              void* d_out, int out_size, void* d_ws, size_t ws_size,
                              hipStream_t stream) {
    const float* boxes   = (const float*)d_in[0];
    // d_in[1] = gt_labels_3d (unused by the reference output)
    const float* teacher = (const float*)d_in[2];
    const float* student = (const float*)d_in[3];
    const float* conv_w  = (const float*)d_in[4];
    const float* conv_b  = (const float*)d_in[5];
    float* out = (float*)d_out;

    int N = in_sizes[0] / 9;
    if (N > 128) N = 128;

    float* wsF     = (float*)d_ws;
    float* partial = wsF;
    float* hmv     = wsF + 1024;
    // ws need: (1024 + 32768) * 4 B = 135 KB

    k_heat<<<HB, 256, 0, stream>>>(boxes, N, hmv, partial);
    k_gemm<<<NSP / 64, 256, 0, stream>>>(student, teacher, conv_w, conv_b,
                                         hmv, partial, out);
}